// Round 7
// baseline (278.469 us; speedup 1.0000x reference)
//
#include <hip/hip_runtime.h>

#define IN_SIZE 256
#define OUT_SIZE 64
#define BSHIFT 7         // 128-row buckets
#define BROWS 128
#define BMASK 127
#define CAP 2560         // bucket capacity: mean 2046, sigma 45 -> +11 sigma
#define K1_EDGES 8192    // edges per coarse block (16 per thread, 512 threads)
#define WPAD 264         // 256+8 shorts, breaks LDS bank alias for W tile

typedef __attribute__((ext_vector_type(8))) short short8;   // 8 bf16, 4 VGPRs
typedef __attribute__((ext_vector_type(4))) float floatx4;  // MFMA acc

__device__ inline unsigned short f2bf(float f) {
  unsigned u = __builtin_bit_cast(unsigned, f);
  u += 0x7fff + ((u >> 16) & 1);  // round-to-nearest-even
  return (unsigned short)(u >> 16);
}
__device__ inline float bf2f(unsigned short u) {
  unsigned v = (unsigned)u << 16;
  return __builtin_bit_cast(float, v);
}

// ---------------------------------------------------------------------------
// K0: zero the coarse cursors.
__global__ __launch_bounds__(512) void zero_kernel(int* __restrict__ cursor) {
  int i = blockIdx.x * 512 + threadIdx.x;
  if (i < 1024) cursor[i] = 0;
}

// ---------------------------------------------------------------------------
// K1: heterogeneous grid (round-3 config). Blocks [0, nb_coarse): coarse
// bucketing by row>>7. Blocks [nb_coarse, ...): xwb = bf16(x @ W.T) with NO
// dinv (deferred to gather) -- keeps matmul independent of bucketing.
struct K1SM {
  union {
    int hist[1024];                 // coarse path (nbuck=782 <= 1024)
    unsigned short w[64 * WPAD];    // matmul path: W tile bf16 (33.8 KB)
  };
};

__global__ __launch_bounds__(512) void fused1_kernel(
    const int* __restrict__ row, const int* __restrict__ col,
    int* __restrict__ coarse_cursor, unsigned* __restrict__ pairs,
    const float* __restrict__ x, const float* __restrict__ W,
    unsigned short* __restrict__ xwb, int n_edges, int n_nodes, int nbuck,
    int nb_coarse) {
  __shared__ K1SM sm;
  int tid = threadIdx.x;
  int bid = blockIdx.x;

  if (bid < nb_coarse) {
    // ---- coarse bucketing ----
    sm.hist[tid] = 0;
    sm.hist[tid + 512] = 0;
    __syncthreads();

    int r[16], c[16];
    int ebase = bid * K1_EDGES + tid;
#pragma unroll
    for (int i = 0; i < 16; i++) {
      int e = ebase + i * 512;
      bool ok = e < n_edges;
      r[i] = ok ? row[e] : -1;
      c[i] = ok ? col[e] : -1;
      if (ok && r[i] != c[i]) atomicAdd(&sm.hist[r[i] >> BSHIFT], 1);
    }
    __syncthreads();

    for (int i = tid; i < nbuck; i += 512) {
      int cnt = sm.hist[i];
      if (cnt) sm.hist[i] = atomicAdd(&coarse_cursor[i], cnt);
    }
    __syncthreads();

#pragma unroll
    for (int i = 0; i < 16; i++) {
      if (r[i] >= 0 && r[i] != c[i]) {
        int bin = r[i] >> BSHIFT;
        int slot = atomicAdd(&sm.hist[bin], 1);
        if (slot < CAP)
          pairs[(size_t)bin * CAP + slot] =
              ((unsigned)(r[i] & BMASK) << 17) | (unsigned)c[i];
      }
    }
  } else {
    // ---- matmul: 128 nodes per block, W converted fp32->bf16 inline ----
    int mb = bid - nb_coarse;
    long nbase = (long)mb * 128;
    {
      int r = tid >> 3;  // 0..63
      int q = tid & 7;   // 8 chunks of 32 floats
      const float* src = W + (size_t)r * IN_SIZE + q * 32;
#pragma unroll
      for (int i = 0; i < 4; i++) {
        float4 a = *(const float4*)(src + i * 8);
        float4 b = *(const float4*)(src + i * 8 + 4);
        short8 s;
        s[0] = (short)f2bf(a.x); s[1] = (short)f2bf(a.y);
        s[2] = (short)f2bf(a.z); s[3] = (short)f2bf(a.w);
        s[4] = (short)f2bf(b.x); s[5] = (short)f2bf(b.y);
        s[6] = (short)f2bf(b.z); s[7] = (short)f2bf(b.w);
        *(short8*)(&sm.w[r * WPAD + q * 32 + i * 8]) = s;
      }
    }
    __syncthreads();

    int wave = tid >> 6;
    int lane = tid & 63;
    int quad = lane >> 4;
    int lcol = lane & 15;
    long node = nbase + wave * 16 + lcol;
    long nclamp = (node < (long)n_nodes) ? node : (long)(n_nodes - 1);
    const float* xrow = x + nclamp * IN_SIZE;

    floatx4 acc[4];
#pragma unroll
    for (int t = 0; t < 4; t++) acc[t] = (floatx4){0.f, 0.f, 0.f, 0.f};

#pragma unroll
    for (int kk = 0; kk < 8; kk++) {
      const float* p = xrow + kk * 32 + quad * 8;
      float4 a = *(const float4*)(p);
      float4 bb = *(const float4*)(p + 4);
      short8 bfrag;
      bfrag[0] = (short)f2bf(a.x);  bfrag[1] = (short)f2bf(a.y);
      bfrag[2] = (short)f2bf(a.z);  bfrag[3] = (short)f2bf(a.w);
      bfrag[4] = (short)f2bf(bb.x); bfrag[5] = (short)f2bf(bb.y);
      bfrag[6] = (short)f2bf(bb.z); bfrag[7] = (short)f2bf(bb.w);
#pragma unroll
      for (int t = 0; t < 4; t++) {
        short8 afrag =
            *(const short8*)(&sm.w[(t * 16 + lcol) * WPAD + kk * 32 + quad * 8]);
        acc[t] = __builtin_amdgcn_mfma_f32_16x16x32_bf16(afrag, bfrag, acc[t],
                                                         0, 0, 0);
      }
    }

    if (node < (long)n_nodes) {
#pragma unroll
      for (int t = 0; t < 4; t++) {
        ushort4 sv;
        sv.x = f2bf(acc[t][0]);
        sv.y = f2bf(acc[t][1]);
        sv.z = f2bf(acc[t][2]);
        sv.w = f2bf(acc[t][3]);
        *(ushort4*)(xwb + node * OUT_SIZE + t * 16 + quad * 4) = sv;
      }
    }
  }
}

// ---------------------------------------------------------------------------
// K2: fine CSR build, single-pass (round-0/3 structure verbatim).
__global__ __launch_bounds__(256) void fine_kernel(
    const int* __restrict__ coarse_cursor, const unsigned* __restrict__ pairs,
    unsigned* __restrict__ colsp, int* __restrict__ count,
    int* __restrict__ row_start, float* __restrict__ dinv, int n_nodes) {
  __shared__ unsigned lpair[CAP];  // 10 KB
  __shared__ int hist[BROWS];
  __shared__ int scn[BROWS];
  int tid = threadIdx.x;
  int b = blockIdx.x;
  size_t base = (size_t)b * CAP;
  int n_b = coarse_cursor[b];
  if (n_b > CAP) n_b = CAP;

  if (tid < BROWS) hist[tid] = 0;
  __syncthreads();

  for (int i = tid; i < n_b; i += 256) {  // copy + histogram in one pass
    unsigned p = pairs[base + i];
    lpair[i] = p;
    atomicAdd(&hist[p >> 17], 1);
  }
  __syncthreads();

  if (tid < BROWS) scn[tid] = hist[tid];
  __syncthreads();
  for (int off = 1; off < BROWS; off <<= 1) {
    int t = (tid >= off && tid < BROWS) ? scn[tid - off] : 0;
    __syncthreads();
    if (tid < BROWS) scn[tid] += t;
    __syncthreads();
  }

  if (tid < BROWS) {
    int e = (tid > 0) ? scn[tid - 1] : 0;
    int r = b * BROWS + tid;
    if (r < n_nodes) {
      int deg = hist[tid];
      count[r] = deg;
      row_start[r] = (int)base + e;
      dinv[r] = rsqrtf((float)deg + 1.0f);
    }
    hist[tid] = e;  // becomes scatter cursor
  }
  __syncthreads();

  for (int i = tid; i < n_b; i += 256) {
    unsigned p = lpair[i];
    int slot = atomicAdd(&hist[p >> 17], 1);
    colsp[base + slot] = p & 0x1FFFFu;
  }
}

// ---------------------------------------------------------------------------
// K3: CSR gather, restructured for 2x edge concurrency at the same VGPR
// class. Each block owns 16 rows x ONE 32-channel half (64B = one sector, no
// waste -- unlike round-2's 32B quarter-rows). Lane = (sub 0..15 edge slots,
// cg 0..3 channel groups of 8). Per wave-iteration: 16 slots x 4 rows = 64
// edges in flight (was 32); iterations ~2 (was ~3). colsp/dinv read twice
// (L2-resident, ~+8MB). Round-6 evidence: explicit prefetch is a no-op
// (compiler already schedules it) -- plain loop.
__global__ __launch_bounds__(256) void gather_kernel(
    const int* __restrict__ row_start, const int* __restrict__ count,
    const unsigned* __restrict__ colsp, const float* __restrict__ dinv,
    const unsigned short* __restrict__ xwb, float* __restrict__ out,
    int n_nodes) {
  int lane = threadIdx.x & 63;
  int wave = threadIdx.x >> 6;
  int sub = lane >> 2;  // edge slot 0..15
  int cg = lane & 3;    // channel group 0..3
  int half = blockIdx.x & 1;
  int bb = blockIdx.x >> 1;
  int rb = (bb * 4 + wave) * 4;  // first of 4 rows
  if (rb >= n_nodes) return;
  int coff = half * 32 + cg * 8;  // 8 channels at coff..coff+7

  int start[4], cnt[4];
  int maxc = 0;
#pragma unroll
  for (int i = 0; i < 4; i++) {
    int r = rb + i;
    bool ok = r < n_nodes;
    start[i] = ok ? row_start[r] : 0;
    cnt[i] = ok ? count[r] : 0;
    maxc = max(maxc, cnt[i]);
  }

  float acc[4][8];
#pragma unroll
  for (int i = 0; i < 4; i++)
#pragma unroll
    for (int k = 0; k < 8; k++) acc[i][k] = 0.f;

  if (sub == 0) {  // self-loop terms: dinv[r]*xw[r]
#pragma unroll
    for (int i = 0; i < 4; i++) {
      int r = rb + i;
      if (r < n_nodes) {
        float dv = dinv[r];
        short8 v = *(const short8*)(xwb + (size_t)r * OUT_SIZE + coff);
#pragma unroll
        for (int k = 0; k < 8; k++) acc[i][k] = dv * bf2f((unsigned short)v[k]);
      }
    }
  }

  for (int j = 0; j < maxc; j += 16) {
    int c[4];
    float m[4];
    int idx = j + sub;
#pragma unroll
    for (int i = 0; i < 4; i++) {
      bool act = idx < cnt[i];
      c[i] = act ? (int)colsp[start[i] + idx] : rb;  // dummy -> hot line
      m[i] = act ? dinv[c[i]] : 0.0f;
    }
    short8 v[4];
#pragma unroll
    for (int i = 0; i < 4; i++)
      v[i] = *(const short8*)(xwb + (size_t)c[i] * OUT_SIZE + coff);
#pragma unroll
    for (int i = 0; i < 4; i++)
#pragma unroll
      for (int k = 0; k < 8; k++)
        acc[i][k] += m[i] * bf2f((unsigned short)v[i][k]);
  }

  // reduce across the 16 edge slots (lane bits 2..5)
#pragma unroll
  for (int i = 0; i < 4; i++)
#pragma unroll
    for (int k = 0; k < 8; k++) {
      acc[i][k] += __shfl_xor(acc[i][k], 4);
      acc[i][k] += __shfl_xor(acc[i][k], 8);
      acc[i][k] += __shfl_xor(acc[i][k], 16);
      acc[i][k] += __shfl_xor(acc[i][k], 32);
    }

  if (sub == 0) {  // lanes 0..3 hold the 4 cg results
#pragma unroll
    for (int i = 0; i < 4; i++) {
      int r = rb + i;
      if (r < n_nodes) {
        float dr = dinv[r];
        float* dst = out + (size_t)r * OUT_SIZE + coff;
        *(float4*)(dst) =
            make_float4(dr * acc[i][0], dr * acc[i][1], dr * acc[i][2],
                        dr * acc[i][3]);
        *(float4*)(dst + 4) =
            make_float4(dr * acc[i][4], dr * acc[i][5], dr * acc[i][6],
                        dr * acc[i][7]);
      }
    }
  }
}

// ---------------------------------------------------------------------------
extern "C" void kernel_launch(void* const* d_in, const int* in_sizes, int n_in,
                              void* d_out, int out_size, void* d_ws,
                              size_t ws_size, hipStream_t stream) {
  const int* edge_index = (const int*)d_in[0];
  const float* x = (const float*)d_in[1];
  const float* W = (const float*)d_in[3];

  int n_edges = in_sizes[0] / 2;
  int n_nodes = in_sizes[1] / IN_SIZE;
  const int* row = edge_index;
  const int* col = edge_index + n_edges;
  float* out = (float*)d_out;

  int nbuck = (n_nodes + BROWS - 1) >> BSHIFT;          // 782
  int nb_coarse = (n_edges + K1_EDGES - 1) / K1_EDGES;  // 196
  int nb_mm = (n_nodes + 127) / 128;                    // 782

  // Workspace: count[N] | row_start[N] | dinv[N] | coarse_cursor(4KB) |
  //            pairs[nbuck*CAP u32] | colsp[nbuck*CAP u32] | xwb[N*64 bf16]
  char* ws = (char*)d_ws;
  size_t nb4 = ((size_t)n_nodes * 4 + 15) & ~(size_t)15;
  int* count = (int*)ws;
  int* row_start = (int*)(ws + nb4);
  float* dinv = (float*)(ws + 2 * nb4);
  int* coarse_cursor = (int*)(ws + 3 * nb4);
  size_t pairsB = (size_t)nbuck * CAP * 4;  // 8,007,680 B
  unsigned* pairs = (unsigned*)(ws + 3 * nb4 + 4096);
  unsigned* colsp = (unsigned*)(ws + 3 * nb4 + 4096 + pairsB);
  unsigned short* xwb =
      (unsigned short*)(ws + 3 * nb4 + 4096 + 2 * pairsB);

  zero_kernel<<<2, 512, 0, stream>>>(coarse_cursor);
  fused1_kernel<<<nb_coarse + nb_mm, 512, 0, stream>>>(
      row, col, coarse_cursor, pairs, x, W, xwb, n_edges, n_nodes, nbuck,
      nb_coarse);
  fine_kernel<<<nbuck, 256, 0, stream>>>(coarse_cursor, pairs, colsp, count,
                                         row_start, dinv, n_nodes);
  int ngb = ((n_nodes + 15) / 16) * 2;  // 2 channel-halves per 16-row group
  gather_kernel<<<ngb, 256, 0, stream>>>(row_start, count, colsp, dinv, xwb,
                                         out, n_nodes);
}

// Round 8
// 261.991 us; speedup vs baseline: 1.0629x; 1.0629x over previous
//
#include <hip/hip_runtime.h>

#define IN_SIZE 256
#define OUT_SIZE 64
#define BSHIFT 7         // 128-row buckets
#define BROWS 128
#define BMASK 127
#define CAP 2560         // bucket capacity: mean 2046, sigma 45 -> +11 sigma
#define K1_EDGES 8192    // edges per coarse block (16 per thread, 512 threads)
#define WPAD 264         // 256+8 shorts, breaks LDS bank alias for W tile
#define MMROWS 256       // nodes per matmul block (2 x 128-row groups, W staged once)

typedef __attribute__((ext_vector_type(8))) short short8;   // 8 bf16, 4 VGPRs
typedef __attribute__((ext_vector_type(4))) float floatx4;  // MFMA acc

__device__ inline unsigned short f2bf(float f) {
  unsigned u = __builtin_bit_cast(unsigned, f);
  u += 0x7fff + ((u >> 16) & 1);  // round-to-nearest-even
  return (unsigned short)(u >> 16);
}
__device__ inline float bf2f(unsigned short u) {
  unsigned v = (unsigned)u << 16;
  return __builtin_bit_cast(float, v);
}

// ---------------------------------------------------------------------------
// K0: zero the coarse cursors.
__global__ __launch_bounds__(512) void zero_kernel(int* __restrict__ cursor) {
  int i = blockIdx.x * 512 + threadIdx.x;
  if (i < 1024) cursor[i] = 0;
}

// ---------------------------------------------------------------------------
// K1: heterogeneous grid. Blocks [0, nb_coarse): coarse bucketing by row>>7.
// Blocks [nb_coarse, ...): xwb = bf16(x @ W.T) with NO dinv (deferred to
// gather). Round-8 change: matmul blocks own 256 rows -- W staged to LDS
// once, two 128-row groups computed from it (halves the 50MB W re-read and
// the stage/sync overhead; 587 total blocks, still ~4/CU resident by LDS).
struct K1SM {
  union {
    int hist[1024];                 // coarse path (nbuck=782 <= 1024)
    unsigned short w[64 * WPAD];    // matmul path: W tile bf16 (33.8 KB)
  };
};

__global__ __launch_bounds__(512) void fused1_kernel(
    const int* __restrict__ row, const int* __restrict__ col,
    int* __restrict__ coarse_cursor, unsigned* __restrict__ pairs,
    const float* __restrict__ x, const float* __restrict__ W,
    unsigned short* __restrict__ xwb, int n_edges, int n_nodes, int nbuck,
    int nb_coarse) {
  __shared__ K1SM sm;
  int tid = threadIdx.x;
  int bid = blockIdx.x;

  if (bid < nb_coarse) {
    // ---- coarse bucketing ----
    sm.hist[tid] = 0;
    sm.hist[tid + 512] = 0;
    __syncthreads();

    int r[16], c[16];
    int ebase = bid * K1_EDGES + tid;
#pragma unroll
    for (int i = 0; i < 16; i++) {
      int e = ebase + i * 512;
      bool ok = e < n_edges;
      r[i] = ok ? row[e] : -1;
      c[i] = ok ? col[e] : -1;
      if (ok && r[i] != c[i]) atomicAdd(&sm.hist[r[i] >> BSHIFT], 1);
    }
    __syncthreads();

    for (int i = tid; i < nbuck; i += 512) {
      int cnt = sm.hist[i];
      if (cnt) sm.hist[i] = atomicAdd(&coarse_cursor[i], cnt);
    }
    __syncthreads();

#pragma unroll
    for (int i = 0; i < 16; i++) {
      if (r[i] >= 0 && r[i] != c[i]) {
        int bin = r[i] >> BSHIFT;
        int slot = atomicAdd(&sm.hist[bin], 1);
        if (slot < CAP)
          pairs[(size_t)bin * CAP + slot] =
              ((unsigned)(r[i] & BMASK) << 17) | (unsigned)c[i];
      }
    }
  } else {
    // ---- matmul: 256 nodes per block, W converted fp32->bf16 inline ----
    int mb = bid - nb_coarse;
    {
      int r = tid >> 3;  // 0..63
      int q = tid & 7;   // 8 chunks of 32 floats
      const float* src = W + (size_t)r * IN_SIZE + q * 32;
#pragma unroll
      for (int i = 0; i < 4; i++) {
        float4 a = *(const float4*)(src + i * 8);
        float4 b = *(const float4*)(src + i * 8 + 4);
        short8 s;
        s[0] = (short)f2bf(a.x); s[1] = (short)f2bf(a.y);
        s[2] = (short)f2bf(a.z); s[3] = (short)f2bf(a.w);
        s[4] = (short)f2bf(b.x); s[5] = (short)f2bf(b.y);
        s[6] = (short)f2bf(b.z); s[7] = (short)f2bf(b.w);
        *(short8*)(&sm.w[r * WPAD + q * 32 + i * 8]) = s;
      }
    }
    __syncthreads();

    int wave = tid >> 6;
    int lane = tid & 63;
    int quad = lane >> 4;
    int lcol = lane & 15;

#pragma unroll
    for (int g = 0; g < 2; g++) {  // two 128-row groups reuse the W tile
      long node = (long)mb * MMROWS + g * 128 + wave * 16 + lcol;
      long nclamp = (node < (long)n_nodes) ? node : (long)(n_nodes - 1);
      const float* xrow = x + nclamp * IN_SIZE;

      floatx4 acc[4];
#pragma unroll
      for (int t = 0; t < 4; t++) acc[t] = (floatx4){0.f, 0.f, 0.f, 0.f};

#pragma unroll
      for (int kk = 0; kk < 8; kk++) {
        const float* p = xrow + kk * 32 + quad * 8;
        float4 a = *(const float4*)(p);
        float4 bb = *(const float4*)(p + 4);
        short8 bfrag;
        bfrag[0] = (short)f2bf(a.x);  bfrag[1] = (short)f2bf(a.y);
        bfrag[2] = (short)f2bf(a.z);  bfrag[3] = (short)f2bf(a.w);
        bfrag[4] = (short)f2bf(bb.x); bfrag[5] = (short)f2bf(bb.y);
        bfrag[6] = (short)f2bf(bb.z); bfrag[7] = (short)f2bf(bb.w);
#pragma unroll
        for (int t = 0; t < 4; t++) {
          short8 afrag = *(const short8*)(
              &sm.w[(t * 16 + lcol) * WPAD + kk * 32 + quad * 8]);
          acc[t] = __builtin_amdgcn_mfma_f32_16x16x32_bf16(afrag, bfrag,
                                                           acc[t], 0, 0, 0);
        }
      }

      if (node < (long)n_nodes) {
#pragma unroll
        for (int t = 0; t < 4; t++) {
          ushort4 sv;
          sv.x = f2bf(acc[t][0]);
          sv.y = f2bf(acc[t][1]);
          sv.z = f2bf(acc[t][2]);
          sv.w = f2bf(acc[t][3]);
          *(ushort4*)(xwb + node * OUT_SIZE + t * 16 + quad * 4) = sv;
        }
      }
    }
  }
}

// ---------------------------------------------------------------------------
// K2: fine CSR build, single-pass (round-0/3 structure verbatim).
__global__ __launch_bounds__(256) void fine_kernel(
    const int* __restrict__ coarse_cursor, const unsigned* __restrict__ pairs,
    unsigned* __restrict__ colsp, int* __restrict__ count,
    int* __restrict__ row_start, float* __restrict__ dinv, int n_nodes) {
  __shared__ unsigned lpair[CAP];  // 10 KB
  __shared__ int hist[BROWS];
  __shared__ int scn[BROWS];
  int tid = threadIdx.x;
  int b = blockIdx.x;
  size_t base = (size_t)b * CAP;
  int n_b = coarse_cursor[b];
  if (n_b > CAP) n_b = CAP;

  if (tid < BROWS) hist[tid] = 0;
  __syncthreads();

  for (int i = tid; i < n_b; i += 256) {  // copy + histogram in one pass
    unsigned p = pairs[base + i];
    lpair[i] = p;
    atomicAdd(&hist[p >> 17], 1);
  }
  __syncthreads();

  if (tid < BROWS) scn[tid] = hist[tid];
  __syncthreads();
  for (int off = 1; off < BROWS; off <<= 1) {
    int t = (tid >= off && tid < BROWS) ? scn[tid - off] : 0;
    __syncthreads();
    if (tid < BROWS) scn[tid] += t;
    __syncthreads();
  }

  if (tid < BROWS) {
    int e = (tid > 0) ? scn[tid - 1] : 0;
    int r = b * BROWS + tid;
    if (r < n_nodes) {
      int deg = hist[tid];
      count[r] = deg;
      row_start[r] = (int)base + e;
      dinv[r] = rsqrtf((float)deg + 1.0f);
    }
    hist[tid] = e;  // becomes scatter cursor
  }
  __syncthreads();

  for (int i = tid; i < n_b; i += 256) {
    unsigned p = lpair[i];
    int slot = atomicAdd(&hist[p >> 17], 1);
    colsp[base + slot] = p & 0x1FFFFu;
  }
}

// ---------------------------------------------------------------------------
// K3: CSR gather -- round-3 structure VERBATIM (the proven 66us local
// optimum: full 128B row per edge, 8 slots x 8 cg, 4 rows/wave, 48 VGPR).
// Rounds 4/6/7 established: 2-edge unroll (VGPR 64, occ 36%) regresses;
// explicit SW prefetch is a compiler no-op; channel-half split doubles
// FETCH (64B half reads pull full 128B lines into different XCDs' L2s).
__global__ __launch_bounds__(256) void gather_kernel(
    const int* __restrict__ row_start, const int* __restrict__ count,
    const unsigned* __restrict__ colsp, const float* __restrict__ dinv,
    const unsigned short* __restrict__ xwb, float* __restrict__ out,
    int n_nodes) {
  int lane = threadIdx.x & 63;
  int wave = threadIdx.x >> 6;
  int sub = lane & 7;   // edge slot
  int cg = lane >> 3;   // channels cg*8 .. cg*8+7
  int rb = (blockIdx.x * 4 + wave) * 4;  // first of 4 rows
  if (rb >= n_nodes) return;

  int start[4], cnt[4];
  int maxc = 0;
#pragma unroll
  for (int i = 0; i < 4; i++) {
    int r = rb + i;
    bool ok = r < n_nodes;
    start[i] = ok ? row_start[r] : 0;
    cnt[i] = ok ? count[r] : 0;
    maxc = max(maxc, cnt[i]);
  }

  float acc[4][8];
#pragma unroll
  for (int i = 0; i < 4; i++)
#pragma unroll
    for (int k = 0; k < 8; k++) acc[i][k] = 0.f;

  if (sub == 0) {  // self-loop terms: dinv[r]*xw[r]
#pragma unroll
    for (int i = 0; i < 4; i++) {
      int r = rb + i;
      if (r < n_nodes) {
        float dv = dinv[r];
        short8 v = *(const short8*)(xwb + (size_t)r * OUT_SIZE + cg * 8);
#pragma unroll
        for (int k = 0; k < 8; k++) acc[i][k] = dv * bf2f((unsigned short)v[k]);
      }
    }
  }

  for (int j = 0; j < maxc; j += 8) {
    int c[4];
    float m[4];
    int idx = j + sub;
#pragma unroll
    for (int i = 0; i < 4; i++) {
      bool act = idx < cnt[i];
      c[i] = act ? (int)colsp[start[i] + idx] : rb;  // dummy -> hot line
      m[i] = act ? dinv[c[i]] : 0.0f;
    }
    short8 v[4];
#pragma unroll
    for (int i = 0; i < 4; i++)
      v[i] = *(const short8*)(xwb + (size_t)c[i] * OUT_SIZE + cg * 8);
#pragma unroll
    for (int i = 0; i < 4; i++)
#pragma unroll
      for (int k = 0; k < 8; k++)
        acc[i][k] += m[i] * bf2f((unsigned short)v[i][k]);
  }

#pragma unroll
  for (int i = 0; i < 4; i++)
#pragma unroll
    for (int k = 0; k < 8; k++) {
      acc[i][k] += __shfl_xor(acc[i][k], 1);
      acc[i][k] += __shfl_xor(acc[i][k], 2);
      acc[i][k] += __shfl_xor(acc[i][k], 4);
    }

  if (sub == 0) {
#pragma unroll
    for (int i = 0; i < 4; i++) {
      int r = rb + i;
      if (r < n_nodes) {
        float dr = dinv[r];
        float* dst = out + (size_t)r * OUT_SIZE + cg * 8;
        *(float4*)(dst) =
            make_float4(dr * acc[i][0], dr * acc[i][1], dr * acc[i][2],
                        dr * acc[i][3]);
        *(float4*)(dst + 4) =
            make_float4(dr * acc[i][4], dr * acc[i][5], dr * acc[i][6],
                        dr * acc[i][7]);
      }
    }
  }
}

// ---------------------------------------------------------------------------
extern "C" void kernel_launch(void* const* d_in, const int* in_sizes, int n_in,
                              void* d_out, int out_size, void* d_ws,
                              size_t ws_size, hipStream_t stream) {
  const int* edge_index = (const int*)d_in[0];
  const float* x = (const float*)d_in[1];
  const float* W = (const float*)d_in[3];

  int n_edges = in_sizes[0] / 2;
  int n_nodes = in_sizes[1] / IN_SIZE;
  const int* row = edge_index;
  const int* col = edge_index + n_edges;
  float* out = (float*)d_out;

  int nbuck = (n_nodes + BROWS - 1) >> BSHIFT;            // 782
  int nb_coarse = (n_edges + K1_EDGES - 1) / K1_EDGES;    // 196
  int nb_mm = (n_nodes + MMROWS - 1) / MMROWS;            // 391

  // Workspace: count[N] | row_start[N] | dinv[N] | coarse_cursor(4KB) |
  //            pairs[nbuck*CAP u32] | colsp[nbuck*CAP u32] | xwb[N*64 bf16]
  char* ws = (char*)d_ws;
  size_t nb4 = ((size_t)n_nodes * 4 + 15) & ~(size_t)15;
  int* count = (int*)ws;
  int* row_start = (int*)(ws + nb4);
  float* dinv = (float*)(ws + 2 * nb4);
  int* coarse_cursor = (int*)(ws + 3 * nb4);
  size_t pairsB = (size_t)nbuck * CAP * 4;  // 8,007,680 B
  unsigned* pairs = (unsigned*)(ws + 3 * nb4 + 4096);
  unsigned* colsp = (unsigned*)(ws + 3 * nb4 + 4096 + pairsB);
  unsigned short* xwb =
      (unsigned short*)(ws + 3 * nb4 + 4096 + 2 * pairsB);

  zero_kernel<<<2, 512, 0, stream>>>(coarse_cursor);
  fused1_kernel<<<nb_coarse + nb_mm, 512, 0, stream>>>(
      row, col, coarse_cursor, pairs, x, W, xwb, n_edges, n_nodes, nbuck,
      nb_coarse);
  fine_kernel<<<nbuck, 256, 0, stream>>>(coarse_cursor, pairs, colsp, count,
                                         row_start, dinv, n_nodes);
  gather_kernel<<<(n_nodes + 15) / 16, 256, 0, stream>>>(
      row_start, count, colsp, dinv, xwb, out, n_nodes);
}

// Round 9
// 256.330 us; speedup vs baseline: 1.0864x; 1.0221x over previous
//
#include <hip/hip_runtime.h>

#define IN_SIZE 256
#define OUT_SIZE 64
#define BSHIFT 7         // 128-row buckets
#define BROWS 128
#define BMASK 127
#define CAP 2560         // bucket capacity: mean 2046, sigma 45 -> +11 sigma
#define K1_EDGES 8192    // edges per coarse block (16 per thread, 512 threads)
#define WPAD 266         // 266 shorts = 133 dwords = 5 mod 32: ~2-way b128
                         // conflicts (free) vs 264's 132=4 mod 32 (8-way, 5.4M
                         // conflict cycles measured in round 8)

typedef __attribute__((ext_vector_type(8))) short short8;   // 8 bf16, 4 VGPRs
typedef __attribute__((ext_vector_type(4))) float floatx4;  // MFMA acc

__device__ inline unsigned short f2bf(float f) {
  unsigned u = __builtin_bit_cast(unsigned, f);
  u += 0x7fff + ((u >> 16) & 1);  // round-to-nearest-even
  return (unsigned short)(u >> 16);
}
__device__ inline float bf2f(unsigned short u) {
  unsigned v = (unsigned)u << 16;
  return __builtin_bit_cast(float, v);
}

// ---------------------------------------------------------------------------
// K0: zero the coarse cursors.
__global__ __launch_bounds__(512) void zero_kernel(int* __restrict__ cursor) {
  int i = blockIdx.x * 512 + threadIdx.x;
  if (i < 1024) cursor[i] = 0;
}

// ---------------------------------------------------------------------------
// K1: heterogeneous grid. Blocks [0, nb_coarse): coarse bucketing by row>>7.
// Blocks [nb_coarse, ...): xwb = bf16(x @ W.T), NO dinv (deferred to gather).
// Round-9 matmul fix: round-8 PMC showed VGPR=32 / VALU 5.9% / HBM 15% --
// MLP-starved (only ~2 kk of loads in flight). Preload the ENTIRE per-lane
// x slice (16 float4 = 64 VGPRs) before the MFMA loop and pin it with
// sched_barrier so the scheduler can't sink the loads; 256B/lane in flight
// turns the kernel HBM-bound. MMROWS=256 reverted (cost 11us).
struct K1SM {
  union {
    int hist[1024];                 // coarse path (nbuck=782 <= 1024)
    unsigned short w[64 * WPAD];    // matmul path: W tile bf16 (34 KB)
  };
};

__global__ __launch_bounds__(512) void fused1_kernel(
    const int* __restrict__ row, const int* __restrict__ col,
    int* __restrict__ coarse_cursor, unsigned* __restrict__ pairs,
    const float* __restrict__ x, const float* __restrict__ W,
    unsigned short* __restrict__ xwb, int n_edges, int n_nodes, int nbuck,
    int nb_coarse) {
  __shared__ K1SM sm;
  int tid = threadIdx.x;
  int bid = blockIdx.x;

  if (bid < nb_coarse) {
    // ---- coarse bucketing ----
    sm.hist[tid] = 0;
    sm.hist[tid + 512] = 0;
    __syncthreads();

    int r[16], c[16];
    int ebase = bid * K1_EDGES + tid;
#pragma unroll
    for (int i = 0; i < 16; i++) {
      int e = ebase + i * 512;
      bool ok = e < n_edges;
      r[i] = ok ? row[e] : -1;
      c[i] = ok ? col[e] : -1;
      if (ok && r[i] != c[i]) atomicAdd(&sm.hist[r[i] >> BSHIFT], 1);
    }
    __syncthreads();

    for (int i = tid; i < nbuck; i += 512) {
      int cnt = sm.hist[i];
      if (cnt) sm.hist[i] = atomicAdd(&coarse_cursor[i], cnt);
    }
    __syncthreads();

#pragma unroll
    for (int i = 0; i < 16; i++) {
      if (r[i] >= 0 && r[i] != c[i]) {
        int bin = r[i] >> BSHIFT;
        int slot = atomicAdd(&sm.hist[bin], 1);
        if (slot < CAP)
          pairs[(size_t)bin * CAP + slot] =
              ((unsigned)(r[i] & BMASK) << 17) | (unsigned)c[i];
      }
    }
  } else {
    // ---- matmul: 128 nodes per block, W converted fp32->bf16 inline ----
    int mb = bid - nb_coarse;
    long nbase = (long)mb * 128;
    {
      int r = tid >> 3;  // 0..63
      int q = tid & 7;   // 8 chunks of 32 floats
      const float* src = W + (size_t)r * IN_SIZE + q * 32;
#pragma unroll
      for (int i = 0; i < 4; i++) {
        float4 a = *(const float4*)(src + i * 8);
        float4 b = *(const float4*)(src + i * 8 + 4);
        short8 s;
        s[0] = (short)f2bf(a.x); s[1] = (short)f2bf(a.y);
        s[2] = (short)f2bf(a.z); s[3] = (short)f2bf(a.w);
        s[4] = (short)f2bf(b.x); s[5] = (short)f2bf(b.y);
        s[6] = (short)f2bf(b.z); s[7] = (short)f2bf(b.w);
        *(short8*)(&sm.w[r * WPAD + q * 32 + i * 8]) = s;
      }
    }
    __syncthreads();

    int wave = tid >> 6;
    int lane = tid & 63;
    int quad = lane >> 4;
    int lcol = lane & 15;
    long node = nbase + wave * 16 + lcol;
    long nclamp = (node < (long)n_nodes) ? node : (long)(n_nodes - 1);
    const float* xrow = x + nclamp * IN_SIZE;

    // Preload the full per-lane x slice: 16 float4 = 64 VGPRs, all 16 loads
    // issued back-to-back -> 256B/lane outstanding (the MLP unlock).
    float4 px[16];
#pragma unroll
    for (int kk = 0; kk < 8; kk++) {
      const float* p = xrow + kk * 32 + quad * 8;
      px[2 * kk] = *(const float4*)(p);
      px[2 * kk + 1] = *(const float4*)(p + 4);
    }
    __builtin_amdgcn_sched_barrier(0);  // don't sink the loads into the loop

    floatx4 acc[4];
#pragma unroll
    for (int t = 0; t < 4; t++) acc[t] = (floatx4){0.f, 0.f, 0.f, 0.f};

#pragma unroll
    for (int kk = 0; kk < 8; kk++) {
      float4 a = px[2 * kk];
      float4 bb = px[2 * kk + 1];
      short8 bfrag;
      bfrag[0] = (short)f2bf(a.x);  bfrag[1] = (short)f2bf(a.y);
      bfrag[2] = (short)f2bf(a.z);  bfrag[3] = (short)f2bf(a.w);
      bfrag[4] = (short)f2bf(bb.x); bfrag[5] = (short)f2bf(bb.y);
      bfrag[6] = (short)f2bf(bb.z); bfrag[7] = (short)f2bf(bb.w);
#pragma unroll
      for (int t = 0; t < 4; t++) {
        short8 afrag =
            *(const short8*)(&sm.w[(t * 16 + lcol) * WPAD + kk * 32 + quad * 8]);
        acc[t] = __builtin_amdgcn_mfma_f32_16x16x32_bf16(afrag, bfrag, acc[t],
                                                         0, 0, 0);
      }
    }

    if (node < (long)n_nodes) {
#pragma unroll
      for (int t = 0; t < 4; t++) {
        ushort4 sv;
        sv.x = f2bf(acc[t][0]);
        sv.y = f2bf(acc[t][1]);
        sv.z = f2bf(acc[t][2]);
        sv.w = f2bf(acc[t][3]);
        *(ushort4*)(xwb + node * OUT_SIZE + t * 16 + quad * 4) = sv;
      }
    }
  }
}

// ---------------------------------------------------------------------------
// K2: fine CSR build, single-pass (round-0/3 structure verbatim).
__global__ __launch_bounds__(256) void fine_kernel(
    const int* __restrict__ coarse_cursor, const unsigned* __restrict__ pairs,
    unsigned* __restrict__ colsp, int* __restrict__ count,
    int* __restrict__ row_start, float* __restrict__ dinv, int n_nodes) {
  __shared__ unsigned lpair[CAP];  // 10 KB
  __shared__ int hist[BROWS];
  __shared__ int scn[BROWS];
  int tid = threadIdx.x;
  int b = blockIdx.x;
  size_t base = (size_t)b * CAP;
  int n_b = coarse_cursor[b];
  if (n_b > CAP) n_b = CAP;

  if (tid < BROWS) hist[tid] = 0;
  __syncthreads();

  for (int i = tid; i < n_b; i += 256) {  // copy + histogram in one pass
    unsigned p = pairs[base + i];
    lpair[i] = p;
    atomicAdd(&hist[p >> 17], 1);
  }
  __syncthreads();

  if (tid < BROWS) scn[tid] = hist[tid];
  __syncthreads();
  for (int off = 1; off < BROWS; off <<= 1) {
    int t = (tid >= off && tid < BROWS) ? scn[tid - off] : 0;
    __syncthreads();
    if (tid < BROWS) scn[tid] += t;
    __syncthreads();
  }

  if (tid < BROWS) {
    int e = (tid > 0) ? scn[tid - 1] : 0;
    int r = b * BROWS + tid;
    if (r < n_nodes) {
      int deg = hist[tid];
      count[r] = deg;
      row_start[r] = (int)base + e;
      dinv[r] = rsqrtf((float)deg + 1.0f);
    }
    hist[tid] = e;  // becomes scatter cursor
  }
  __syncthreads();

  for (int i = tid; i < n_b; i += 256) {
    unsigned p = lpair[i];
    int slot = atomicAdd(&hist[p >> 17], 1);
    colsp[base + slot] = p & 0x1FFFFu;
  }
}

// ---------------------------------------------------------------------------
// K3: CSR gather -- round-3 structure VERBATIM (proven 66us local optimum:
// full 128B row per edge, 8 slots x 8 cg, 4 rows/wave, 48 VGPR, occ 45%).
// Refuted alternatives: 2-edge unroll (r4: VGPR 64, occ 36%, +4us); SW
// prefetch (r6: compiler no-op); channel-half split (r7: FETCH x2, +25us).
__global__ __launch_bounds__(256) void gather_kernel(
    const int* __restrict__ row_start, const int* __restrict__ count,
    const unsigned* __restrict__ colsp, const float* __restrict__ dinv,
    const unsigned short* __restrict__ xwb, float* __restrict__ out,
    int n_nodes) {
  int lane = threadIdx.x & 63;
  int wave = threadIdx.x >> 6;
  int sub = lane & 7;   // edge slot
  int cg = lane >> 3;   // channels cg*8 .. cg*8+7
  int rb = (blockIdx.x * 4 + wave) * 4;  // first of 4 rows
  if (rb >= n_nodes) return;

  int start[4], cnt[4];
  int maxc = 0;
#pragma unroll
  for (int i = 0; i < 4; i++) {
    int r = rb + i;
    bool ok = r < n_nodes;
    start[i] = ok ? row_start[r] : 0;
    cnt[i] = ok ? count[r] : 0;
    maxc = max(maxc, cnt[i]);
  }

  float acc[4][8];
#pragma unroll
  for (int i = 0; i < 4; i++)
#pragma unroll
    for (int k = 0; k < 8; k++) acc[i][k] = 0.f;

  if (sub == 0) {  // self-loop terms: dinv[r]*xw[r]
#pragma unroll
    for (int i = 0; i < 4; i++) {
      int r = rb + i;
      if (r < n_nodes) {
        float dv = dinv[r];
        short8 v = *(const short8*)(xwb + (size_t)r * OUT_SIZE + cg * 8);
#pragma unroll
        for (int k = 0; k < 8; k++) acc[i][k] = dv * bf2f((unsigned short)v[k]);
      }
    }
  }

  for (int j = 0; j < maxc; j += 8) {
    int c[4];
    float m[4];
    int idx = j + sub;
#pragma unroll
    for (int i = 0; i < 4; i++) {
      bool act = idx < cnt[i];
      c[i] = act ? (int)colsp[start[i] + idx] : rb;  // dummy -> hot line
      m[i] = act ? dinv[c[i]] : 0.0f;
    }
    short8 v[4];
#pragma unroll
    for (int i = 0; i < 4; i++)
      v[i] = *(const short8*)(xwb + (size_t)c[i] * OUT_SIZE + cg * 8);
#pragma unroll
    for (int i = 0; i < 4; i++)
#pragma unroll
      for (int k = 0; k < 8; k++)
        acc[i][k] += m[i] * bf2f((unsigned short)v[i][k]);
  }

#pragma unroll
  for (int i = 0; i < 4; i++)
#pragma unroll
    for (int k = 0; k < 8; k++) {
      acc[i][k] += __shfl_xor(acc[i][k], 1);
      acc[i][k] += __shfl_xor(acc[i][k], 2);
      acc[i][k] += __shfl_xor(acc[i][k], 4);
    }

  if (sub == 0) {
#pragma unroll
    for (int i = 0; i < 4; i++) {
      int r = rb + i;
      if (r < n_nodes) {
        float dr = dinv[r];
        float* dst = out + (size_t)r * OUT_SIZE + cg * 8;
        *(float4*)(dst) =
            make_float4(dr * acc[i][0], dr * acc[i][1], dr * acc[i][2],
                        dr * acc[i][3]);
        *(float4*)(dst + 4) =
            make_float4(dr * acc[i][4], dr * acc[i][5], dr * acc[i][6],
                        dr * acc[i][7]);
      }
    }
  }
}

// ---------------------------------------------------------------------------
extern "C" void kernel_launch(void* const* d_in, const int* in_sizes, int n_in,
                              void* d_out, int out_size, void* d_ws,
                              size_t ws_size, hipStream_t stream) {
  const int* edge_index = (const int*)d_in[0];
  const float* x = (const float*)d_in[1];
  const float* W = (const float*)d_in[3];

  int n_edges = in_sizes[0] / 2;
  int n_nodes = in_sizes[1] / IN_SIZE;
  const int* row = edge_index;
  const int* col = edge_index + n_edges;
  float* out = (float*)d_out;

  int nbuck = (n_nodes + BROWS - 1) >> BSHIFT;          // 782
  int nb_coarse = (n_edges + K1_EDGES - 1) / K1_EDGES;  // 196
  int nb_mm = (n_nodes + 127) / 128;                    // 782

  // Workspace: count[N] | row_start[N] | dinv[N] | coarse_cursor(4KB) |
  //            pairs[nbuck*CAP u32] | colsp[nbuck*CAP u32] | xwb[N*64 bf16]
  char* ws = (char*)d_ws;
  size_t nb4 = ((size_t)n_nodes * 4 + 15) & ~(size_t)15;
  int* count = (int*)ws;
  int* row_start = (int*)(ws + nb4);
  float* dinv = (float*)(ws + 2 * nb4);
  int* coarse_cursor = (int*)(ws + 3 * nb4);
  size_t pairsB = (size_t)nbuck * CAP * 4;  // 8,007,680 B
  unsigned* pairs = (unsigned*)(ws + 3 * nb4 + 4096);
  unsigned* colsp = (unsigned*)(ws + 3 * nb4 + 4096 + pairsB);
  unsigned short* xwb =
      (unsigned short*)(ws + 3 * nb4 + 4096 + 2 * pairsB);

  zero_kernel<<<2, 512, 0, stream>>>(coarse_cursor);
  fused1_kernel<<<nb_coarse + nb_mm, 512, 0, stream>>>(
      row, col, coarse_cursor, pairs, x, W, xwb, n_edges, n_nodes, nbuck,
      nb_coarse);
  fine_kernel<<<nbuck, 256, 0, stream>>>(coarse_cursor, pairs, colsp, count,
                                         row_start, dinv, n_nodes);
  gather_kernel<<<(n_nodes + 15) / 16, 256, 0, stream>>>(
      row_start, count, colsp, dinv, xwb, out, n_nodes);
}

// Round 11
// 254.605 us; speedup vs baseline: 1.0937x; 1.0068x over previous
//
#include <hip/hip_runtime.h>

#define IN_SIZE 256
#define OUT_SIZE 64
#define BSHIFT 7         // 128-row buckets
#define BROWS 128
#define BMASK 127
#define CAP 2560         // bucket capacity: mean 2046, sigma 45 -> +11 sigma
#define K1_EDGES 4096    // edges per coarse block (8/thread; r10: was 8192 --
                         // coarse path IS fused1's critical path, 2x blocks
                         // halves its serial chain and doubles CU coverage)
#define WPAD 264         // 256+8 shorts

typedef __attribute__((ext_vector_type(8))) short short8;   // 8 bf16, 4 VGPRs
typedef __attribute__((ext_vector_type(4))) float floatx4;  // MFMA acc

__device__ inline unsigned short f2bf(float f) {
  unsigned u = __builtin_bit_cast(unsigned, f);
  u += 0x7fff + ((u >> 16) & 1);  // round-to-nearest-even
  return (unsigned short)(u >> 16);
}
__device__ inline float bf2f(unsigned short u) {
  unsigned v = (unsigned)u << 16;
  return __builtin_bit_cast(float, v);
}

// ---------------------------------------------------------------------------
// K0: zero the coarse cursors.
__global__ __launch_bounds__(512) void zero_kernel(int* __restrict__ cursor) {
  int i = blockIdx.x * 512 + threadIdx.x;
  if (i < 1024) cursor[i] = 0;
}

// ---------------------------------------------------------------------------
// K1: heterogeneous grid. Blocks [0, nb_coarse): coarse bucketing by row>>7.
// Blocks [nb_coarse, ...): xwb = bf16(x @ W.T), NO dinv (deferred to gather).
// Evidence (r1/r8/r9): fused1 duration == coarse-path duration; matmul rides
// along free. r9's px-preload was a null-op and is reverted (it only taxes
// the shared VGPR budget). r10: K1_EDGES 4096 -> 391 coarse blocks.
struct K1SM {
  union {
    int hist[1024];                 // coarse path (nbuck=782 <= 1024)
    unsigned short w[64 * WPAD];    // matmul path: W tile bf16 (33.8 KB)
  };
};

__global__ __launch_bounds__(512) void fused1_kernel(
    const int* __restrict__ row, const int* __restrict__ col,
    int* __restrict__ coarse_cursor, unsigned* __restrict__ pairs,
    const float* __restrict__ x, const float* __restrict__ W,
    unsigned short* __restrict__ xwb, int n_edges, int n_nodes, int nbuck,
    int nb_coarse) {
  __shared__ K1SM sm;
  int tid = threadIdx.x;
  int bid = blockIdx.x;

  if (bid < nb_coarse) {
    // ---- coarse bucketing: 4096 edges, 8 per thread ----
    sm.hist[tid] = 0;
    sm.hist[tid + 512] = 0;
    __syncthreads();

    int r[8], c[8];
    int ebase = bid * K1_EDGES + tid;
#pragma unroll
    for (int i = 0; i < 8; i++) {
      int e = ebase + i * 512;
      bool ok = e < n_edges;
      r[i] = ok ? row[e] : -1;
      c[i] = ok ? col[e] : -1;
      if (ok && r[i] != c[i]) atomicAdd(&sm.hist[r[i] >> BSHIFT], 1);
    }
    __syncthreads();

    for (int i = tid; i < nbuck; i += 512) {
      int cnt = sm.hist[i];
      if (cnt) sm.hist[i] = atomicAdd(&coarse_cursor[i], cnt);
    }
    __syncthreads();

#pragma unroll
    for (int i = 0; i < 8; i++) {
      if (r[i] >= 0 && r[i] != c[i]) {
        int bin = r[i] >> BSHIFT;
        int slot = atomicAdd(&sm.hist[bin], 1);
        if (slot < CAP)
          pairs[(size_t)bin * CAP + slot] =
              ((unsigned)(r[i] & BMASK) << 17) | (unsigned)c[i];
      }
    }
  } else {
    // ---- matmul: 128 nodes per block, round-3 body verbatim ----
    int mb = bid - nb_coarse;
    long nbase = (long)mb * 128;
    {
      int r = tid >> 3;  // 0..63
      int q = tid & 7;   // 8 chunks of 32 floats
      const float* src = W + (size_t)r * IN_SIZE + q * 32;
#pragma unroll
      for (int i = 0; i < 4; i++) {
        float4 a = *(const float4*)(src + i * 8);
        float4 b = *(const float4*)(src + i * 8 + 4);
        short8 s;
        s[0] = (short)f2bf(a.x); s[1] = (short)f2bf(a.y);
        s[2] = (short)f2bf(a.z); s[3] = (short)f2bf(a.w);
        s[4] = (short)f2bf(b.x); s[5] = (short)f2bf(b.y);
        s[6] = (short)f2bf(b.z); s[7] = (short)f2bf(b.w);
        *(short8*)(&sm.w[r * WPAD + q * 32 + i * 8]) = s;
      }
    }
    __syncthreads();

    int wave = tid >> 6;
    int lane = tid & 63;
    int quad = lane >> 4;
    int lcol = lane & 15;
    long node = nbase + wave * 16 + lcol;
    long nclamp = (node < (long)n_nodes) ? node : (long)(n_nodes - 1);
    const float* xrow = x + nclamp * IN_SIZE;

    floatx4 acc[4];
#pragma unroll
    for (int t = 0; t < 4; t++) acc[t] = (floatx4){0.f, 0.f, 0.f, 0.f};

#pragma unroll
    for (int kk = 0; kk < 8; kk++) {
      const float* p = xrow + kk * 32 + quad * 8;
      float4 a = *(const float4*)(p);
      float4 bb = *(const float4*)(p + 4);
      short8 bfrag;
      bfrag[0] = (short)f2bf(a.x);  bfrag[1] = (short)f2bf(a.y);
      bfrag[2] = (short)f2bf(a.z);  bfrag[3] = (short)f2bf(a.w);
      bfrag[4] = (short)f2bf(bb.x); bfrag[5] = (short)f2bf(bb.y);
      bfrag[6] = (short)f2bf(bb.z); bfrag[7] = (short)f2bf(bb.w);
#pragma unroll
      for (int t = 0; t < 4; t++) {
        short8 afrag =
            *(const short8*)(&sm.w[(t * 16 + lcol) * WPAD + kk * 32 + quad * 8]);
        acc[t] = __builtin_amdgcn_mfma_f32_16x16x32_bf16(afrag, bfrag, acc[t],
                                                         0, 0, 0);
      }
    }

    if (node < (long)n_nodes) {
#pragma unroll
      for (int t = 0; t < 4; t++) {
        ushort4 sv;
        sv.x = f2bf(acc[t][0]);
        sv.y = f2bf(acc[t][1]);
        sv.z = f2bf(acc[t][2]);
        sv.w = f2bf(acc[t][3]);
        *(ushort4*)(xwb + node * OUT_SIZE + t * 16 + quad * 4) = sv;
      }
    }
  }
}

// ---------------------------------------------------------------------------
// K2: fine CSR build, single-pass; r10: 512 threads (copy/hist/scatter
// strides halve; the 128-bin scan uses tid<128 as before).
__global__ __launch_bounds__(512) void fine_kernel(
    const int* __restrict__ coarse_cursor, const unsigned* __restrict__ pairs,
    unsigned* __restrict__ colsp, int* __restrict__ count,
    int* __restrict__ row_start, float* __restrict__ dinv, int n_nodes) {
  __shared__ unsigned lpair[CAP];  // 10 KB
  __shared__ int hist[BROWS];
  __shared__ int scn[BROWS];
  int tid = threadIdx.x;
  int b = blockIdx.x;
  size_t base = (size_t)b * CAP;
  int n_b = coarse_cursor[b];
  if (n_b > CAP) n_b = CAP;

  if (tid < BROWS) hist[tid] = 0;
  __syncthreads();

  for (int i = tid; i < n_b; i += 512) {  // copy + histogram in one pass
    unsigned p = pairs[base + i];
    lpair[i] = p;
    atomicAdd(&hist[p >> 17], 1);
  }
  __syncthreads();

  if (tid < BROWS) scn[tid] = hist[tid];
  __syncthreads();
  for (int off = 1; off < BROWS; off <<= 1) {
    int t = (tid >= off && tid < BROWS) ? scn[tid - off] : 0;
    __syncthreads();
    if (tid < BROWS) scn[tid] += t;
    __syncthreads();
  }

  if (tid < BROWS) {
    int e = (tid > 0) ? scn[tid - 1] : 0;
    int r = b * BROWS + tid;
    if (r < n_nodes) {
      int deg = hist[tid];
      count[r] = deg;
      row_start[r] = (int)base + e;
      dinv[r] = rsqrtf((float)deg + 1.0f);
    }
    hist[tid] = e;  // becomes scatter cursor
  }
  __syncthreads();

  for (int i = tid; i < n_b; i += 512) {
    unsigned p = lpair[i];
    int slot = atomicAdd(&hist[p >> 17], 1);
    colsp[base + slot] = p & 0x1FFFFu;
  }
}

// ---------------------------------------------------------------------------
// K3: CSR gather -- round-3 structure VERBATIM (proven 65-66us local optimum:
// full 128B row per edge, 8 slots x 8 cg, 4 rows/wave, 48 VGPR, occ 45%).
// Refuted: 2-edge unroll (r4), SW prefetch (r6: compiler no-op),
// channel-half split (r7: FETCH x2).
__global__ __launch_bounds__(256) void gather_kernel(
    const int* __restrict__ row_start, const int* __restrict__ count,
    const unsigned* __restrict__ colsp, const float* __restrict__ dinv,
    const unsigned short* __restrict__ xwb, float* __restrict__ out,
    int n_nodes) {
  int lane = threadIdx.x & 63;
  int wave = threadIdx.x >> 6;
  int sub = lane & 7;   // edge slot
  int cg = lane >> 3;   // channels cg*8 .. cg*8+7
  int rb = (blockIdx.x * 4 + wave) * 4;  // first of 4 rows
  if (rb >= n_nodes) return;

  int start[4], cnt[4];
  int maxc = 0;
#pragma unroll
  for (int i = 0; i < 4; i++) {
    int r = rb + i;
    bool ok = r < n_nodes;
    start[i] = ok ? row_start[r] : 0;
    cnt[i] = ok ? count[r] : 0;
    maxc = max(maxc, cnt[i]);
  }

  float acc[4][8];
#pragma unroll
  for (int i = 0; i < 4; i++)
#pragma unroll
    for (int k = 0; k < 8; k++) acc[i][k] = 0.f;

  if (sub == 0) {  // self-loop terms: dinv[r]*xw[r]
#pragma unroll
    for (int i = 0; i < 4; i++) {
      int r = rb + i;
      if (r < n_nodes) {
        float dv = dinv[r];
        short8 v = *(const short8*)(xwb + (size_t)r * OUT_SIZE + cg * 8);
#pragma unroll
        for (int k = 0; k < 8; k++) acc[i][k] = dv * bf2f((unsigned short)v[k]);
      }
    }
  }

  for (int j = 0; j < maxc; j += 8) {
    int c[4];
    float m[4];
    int idx = j + sub;
#pragma unroll
    for (int i = 0; i < 4; i++) {
      bool act = idx < cnt[i];
      c[i] = act ? (int)colsp[start[i] + idx] : rb;  // dummy -> hot line
      m[i] = act ? dinv[c[i]] : 0.0f;
    }
    short8 v[4];
#pragma unroll
    for (int i = 0; i < 4; i++)
      v[i] = *(const short8*)(xwb + (size_t)c[i] * OUT_SIZE + cg * 8);
#pragma unroll
    for (int i = 0; i < 4; i++)
#pragma unroll
      for (int k = 0; k < 8; k++)
        acc[i][k] += m[i] * bf2f((unsigned short)v[i][k]);
  }

#pragma unroll
  for (int i = 0; i < 4; i++)
#pragma unroll
    for (int k = 0; k < 8; k++) {
      acc[i][k] += __shfl_xor(acc[i][k], 1);
      acc[i][k] += __shfl_xor(acc[i][k], 2);
      acc[i][k] += __shfl_xor(acc[i][k], 4);
    }

  if (sub == 0) {
#pragma unroll
    for (int i = 0; i < 4; i++) {
      int r = rb + i;
      if (r < n_nodes) {
        float dr = dinv[r];
        float* dst = out + (size_t)r * OUT_SIZE + cg * 8;
        *(float4*)(dst) =
            make_float4(dr * acc[i][0], dr * acc[i][1], dr * acc[i][2],
                        dr * acc[i][3]);
        *(float4*)(dst + 4) =
            make_float4(dr * acc[i][4], dr * acc[i][5], dr * acc[i][6],
                        dr * acc[i][7]);
      }
    }
  }
}

// ---------------------------------------------------------------------------
extern "C" void kernel_launch(void* const* d_in, const int* in_sizes, int n_in,
                              void* d_out, int out_size, void* d_ws,
                              size_t ws_size, hipStream_t stream) {
  const int* edge_index = (const int*)d_in[0];
  const float* x = (const float*)d_in[1];
  const float* W = (const float*)d_in[3];

  int n_edges = in_sizes[0] / 2;
  int n_nodes = in_sizes[1] / IN_SIZE;
  const int* row = edge_index;
  const int* col = edge_index + n_edges;
  float* out = (float*)d_out;

  int nbuck = (n_nodes + BROWS - 1) >> BSHIFT;          // 782
  int nb_coarse = (n_edges + K1_EDGES - 1) / K1_EDGES;  // 391
  int nb_mm = (n_nodes + 127) / 128;                    // 782

  // Workspace: count[N] | row_start[N] | dinv[N] | coarse_cursor(4KB) |
  //            pairs[nbuck*CAP u32] | colsp[nbuck*CAP u32] | xwb[N*64 bf16]
  char* ws = (char*)d_ws;
  size_t nb4 = ((size_t)n_nodes * 4 + 15) & ~(size_t)15;
  int* count = (int*)ws;
  int* row_start = (int*)(ws + nb4);
  float* dinv = (float*)(ws + 2 * nb4);
  int* coarse_cursor = (int*)(ws + 3 * nb4);
  size_t pairsB = (size_t)nbuck * CAP * 4;  // 8,007,680 B
  unsigned* pairs = (unsigned*)(ws + 3 * nb4 + 4096);
  unsigned* colsp = (unsigned*)(ws + 3 * nb4 + 4096 + pairsB);
  unsigned short* xwb =
      (unsigned short*)(ws + 3 * nb4 + 4096 + 2 * pairsB);

  zero_kernel<<<2, 512, 0, stream>>>(coarse_cursor);
  fused1_kernel<<<nb_coarse + nb_mm, 512, 0, stream>>>(
      row, col, coarse_cursor, pairs, x, W, xwb, n_edges, n_nodes, nbuck,
      nb_coarse);
  fine_kernel<<<nbuck, 512, 0, stream>>>(coarse_cursor, pairs, colsp, count,
                                         row_start, dinv, n_nodes);
  gather_kernel<<<(n_nodes + 15) / 16, 256, 0, stream>>>(
      row_start, count, colsp, dinv, xwb, out, n_nodes);
}